// Round 8
// baseline (322.595 us; speedup 1.0000x reference)
//
#include <hip/hip_runtime.h>

#define NUM_USERS  150000
#define NUM_ITEMS  140000
#define NUM_BRANDS 10000
#define N_NODES    300000
#define DIM        64
#define N_EDGES    1200000
#define OUT_ROWS   290000          // users + items

#define CHUNK      1024            // elements per scan block
#define NB         ((N_NODES + CHUNK - 1) / CHUNK)   // 293 scan blocks

#define NBIN       8               // one bin per XCD
#define BINSZ      (N_EDGES / NBIN)                  // 150000 csr records

// ---------------------------------------------------------------------------
// non-temporal load/store helpers (ext_vector types for the clang builtin)
// ---------------------------------------------------------------------------
typedef unsigned int u32x4 __attribute__((ext_vector_type(4)));
typedef unsigned int u32x2 __attribute__((ext_vector_type(2)));
typedef float        f32x4 __attribute__((ext_vector_type(4)));

__device__ __forceinline__ uint2 nt_load_u2(const uint2* p) {
    u32x2 v = __builtin_nontemporal_load(reinterpret_cast<const u32x2*>(p));
    return make_uint2(v.x, v.y);
}
__device__ __forceinline__ uint4 nt_load_u4(const uint4* p) {
    u32x4 v = __builtin_nontemporal_load(reinterpret_cast<const u32x4*>(p));
    return make_uint4(v.x, v.y, v.z, v.w);
}
__device__ __forceinline__ void nt_store_u4(uint4* p, uint4 v) {
    u32x4 w; w.x = v.x; w.y = v.y; w.z = v.z; w.w = v.w;
    __builtin_nontemporal_store(w, reinterpret_cast<u32x4*>(p));
}
__device__ __forceinline__ void nt_store_f4(float4* p, float4 v) {
    f32x4 w; w.x = v.x; w.y = v.y; w.z = v.z; w.w = v.w;
    __builtin_nontemporal_store(w, reinterpret_cast<f32x4*>(p));
}

// ---------------------------------------------------------------------------
// bf16 helpers (h1/h2 stored as packed bf16: 64 dims = 8 uint4 per row)
// ---------------------------------------------------------------------------
__device__ __forceinline__ float bf_lo(unsigned u) { return __uint_as_float(u << 16); }
__device__ __forceinline__ float bf_hi(unsigned u) { return __uint_as_float(u & 0xffff0000u); }
__device__ __forceinline__ unsigned pack_bf(float a, float b) {
    unsigned ua = __float_as_uint(a); ua += 0x7fffu + ((ua >> 16) & 1u);
    unsigned ub = __float_as_uint(b); ub += 0x7fffu + ((ub >> 16) & 1u);
    return (ua >> 16) | (ub & 0xffff0000u);
}

// ---------------------------------------------------------------------------
// histogram of destination degrees + per-edge rank within its row
// ---------------------------------------------------------------------------
__global__ void lgcn_hist(const int* __restrict__ dst,
                          int* __restrict__ counts,
                          int* __restrict__ rank) {
    int e = blockIdx.x * blockDim.x + threadIdx.x;
    if (e >= N_EDGES) return;
    rank[e] = atomicAdd(&counts[dst[e]], 1);
}

// ---------------------------------------------------------------------------
// scan phase 1: per-1024-chunk exclusive scan (256 thr x 4 elem), chunk sums
// ---------------------------------------------------------------------------
__global__ void lgcn_scan_p1(const int* __restrict__ counts,
                             int* __restrict__ rowptr,
                             int* __restrict__ blockSums) {
    __shared__ int ts[256];
    int b    = blockIdx.x;
    int base = b * CHUNK;
    int t    = threadIdx.x;
    int c[4];
    int s = 0;
#pragma unroll
    for (int i = 0; i < 4; ++i) {
        int g = base + t * 4 + i;
        c[i] = (g < N_NODES) ? counts[g] : 0;
        s += c[i];
    }
    ts[t] = s;
    __syncthreads();
    for (int off = 1; off < 256; off <<= 1) {
        int v = (t >= off) ? ts[t - off] : 0;
        __syncthreads();
        ts[t] += v;
        __syncthreads();
    }
    int run = ts[t] - s;     // exclusive prefix of this thread's 4-group
#pragma unroll
    for (int i = 0; i < 4; ++i) {
        int g = base + t * 4 + i;
        if (g < N_NODES) rowptr[g] = run;
        run += c[i];
    }
    if (t == 255) blockSums[b] = ts[255];
}

// ---------------------------------------------------------------------------
// scan phase 2: single block exclusive-scans the NB (=293) chunk sums
// ---------------------------------------------------------------------------
__global__ void lgcn_scan_p2(int* __restrict__ blockSums) {
    __shared__ int sh[512];
    int t = threadIdx.x;
    int v = (t < NB) ? blockSums[t] : 0;
    sh[t] = v;
    __syncthreads();
    for (int off = 1; off < 512; off <<= 1) {
        int u = (t >= off) ? sh[t - off] : 0;
        __syncthreads();
        sh[t] += u;
        __syncthreads();
    }
    if (t < NB) blockSums[t] = sh[t] - v;   // exclusive
}

// ---------------------------------------------------------------------------
// scan phase 3: add chunk offsets; rowptr[N_NODES] = N_EDGES
// ---------------------------------------------------------------------------
__global__ void lgcn_scan_p3(int* __restrict__ rowptr,
                             const int* __restrict__ blockSums) {
    int b    = blockIdx.x;
    int base = b * CHUNK;
    int t    = threadIdx.x;
    int off  = blockSums[b];
#pragma unroll
    for (int i = 0; i < 4; ++i) {
        int g = base + t * 4 + i;
        if (g < N_NODES) rowptr[g] += off;
    }
    if (b == 0 && t == 0) rowptr[N_NODES] = N_EDGES;
}

// ---------------------------------------------------------------------------
// XCD-private binned CSR build. Streaming inputs use NON-TEMPORAL loads so
// they don't evict the partially-filled dirty csr lines from L2 (R7's 6.4x
// write-amp was stream-thrash of the dirty bin region).
// ---------------------------------------------------------------------------
__global__ void lgcn_csr_bin(const int*   __restrict__ src,
                             const int*   __restrict__ dst,
                             const float* __restrict__ vals,
                             const int*   __restrict__ rank,
                             const int*   __restrict__ rowptr,
                             uint2*       __restrict__ csr) {
    int b    = blockIdx.x;
    int bin  = b & (NBIN - 1);
    int e    = (b >> 3) * blockDim.x + threadIdx.x;
    if (e >= N_EDGES) return;
    int d  = __builtin_nontemporal_load(dst + e);
    int rk = __builtin_nontemporal_load(rank + e);
    int pos = rowptr[d] + rk;
    int lo  = bin * BINSZ;
    if (pos >= lo && pos < lo + BINSZ) {
        uint2 rec;
        rec.x = (unsigned)__builtin_nontemporal_load(src + e);
        rec.y = __float_as_uint(__builtin_nontemporal_load(vals + e));
        csr[pos] = rec;                 // regular store: keep cached until full
    }
}

// ---------------------------------------------------------------------------
// ego row lookup: concat(user,item,brand) without materializing the concat
// ---------------------------------------------------------------------------
__device__ __forceinline__ const float4* ego_row(const float* __restrict__ user,
                                                 const float* __restrict__ item,
                                                 const float* __restrict__ brand,
                                                 int r) {
    if (r < NUM_USERS)
        return reinterpret_cast<const float4*>(user) + (r << 4);
    else if (r < NUM_USERS + NUM_ITEMS)
        return reinterpret_cast<const float4*>(item) + ((r - NUM_USERS) << 4);
    else
        return reinterpret_cast<const float4*>(brand) + ((r - NUM_USERS - NUM_ITEMS) << 4);
}

// row load, 8 floats per lane (8 lanes per row). Regular (cached) loads —
// these are the random accesses we WANT resident in L2.
template <int LAYER>
__device__ __forceinline__ void load8(const float* __restrict__ user,
                                      const float* __restrict__ item,
                                      const float* __restrict__ brand,
                                      const uint4* __restrict__ h_src,
                                      int r, int q, float4& a, float4& b) {
    if (LAYER == 1) {
        const float4* er = ego_row(user, item, brand, r);
        a = er[2 * q];
        b = er[2 * q + 1];
    } else {
        uint4 w = h_src[(r << 3) + q];
        a = make_float4(bf_lo(w.x), bf_hi(w.x), bf_lo(w.y), bf_hi(w.y));
        b = make_float4(bf_lo(w.z), bf_hi(w.z), bf_lo(w.w), bf_hi(w.w));
    }
}

// ---------------------------------------------------------------------------
// gather SpMM: 8 lanes per dst node (8 dims/lane), 8 nodes per wave.
// 3-deep software pipeline: row load issued 2 iterations ahead, rec load 3
// ahead -> ~2 rows in flight per wave (R7 showed we were concurrency-short).
// csr stream = nt loads; h_out = nt store (protect L2 for random rows).
// ---------------------------------------------------------------------------
template <int LAYER>
__global__ void lgcn_gather(const int*   __restrict__ rowptr,
                            const uint2* __restrict__ csr,
                            const float* __restrict__ user,
                            const float* __restrict__ item,
                            const float* __restrict__ brand,
                            const uint4* __restrict__ h1,
                            const uint4* __restrict__ h2,
                            uint4*       __restrict__ h_out,
                            float*       __restrict__ out) {
    int t    = blockIdx.x * blockDim.x + threadIdx.x;   // node*8 + q
    int node = t >> 3;
    int q    = t & 7;
    int beg = rowptr[node];
    int end = rowptr[node + 1];
    const uint4* h_src = (LAYER == 2) ? h1 : h2;        // LAYER 1 ignores this
    float4 s0 = make_float4(0.f, 0.f, 0.f, 0.f);
    float4 s1 = make_float4(0.f, 0.f, 0.f, 0.f);
    if (beg < end) {
        int last = end - 1;
        uint2 rec0 = nt_load_u2(csr + beg);
        uint2 rec1 = nt_load_u2(csr + (beg + 1 < end ? beg + 1 : last));
        uint2 rec2 = nt_load_u2(csr + (beg + 2 < end ? beg + 2 : last));
        float4 a0, b0, a1, b1;
        load8<LAYER>(user, item, brand, h_src, (int)rec0.x, q, a0, b0);
        load8<LAYER>(user, item, brand, h_src, (int)rec1.x, q, a1, b1);
        for (int j = beg; j < end; ++j) {
            int jn = j + 3 < end ? j + 3 : last;
            uint2 rec3 = nt_load_u2(csr + jn);          // rec, 3 ahead
            float4 a2, b2;                              // row, 2 ahead
            load8<LAYER>(user, item, brand, h_src, (int)rec2.x, q, a2, b2);
            float v = __uint_as_float(rec0.y);
            s0.x = fmaf(a0.x, v, s0.x);
            s0.y = fmaf(a0.y, v, s0.y);
            s0.z = fmaf(a0.z, v, s0.z);
            s0.w = fmaf(a0.w, v, s0.w);
            s1.x = fmaf(b0.x, v, s1.x);
            s1.y = fmaf(b0.y, v, s1.y);
            s1.z = fmaf(b0.z, v, s1.z);
            s1.w = fmaf(b0.w, v, s1.w);
            rec0 = rec1; rec1 = rec2; rec2 = rec3;
            a0 = a1; b0 = b1; a1 = a2; b1 = b2;
        }
    }
    if (LAYER != 3) {
        uint4 w;
        w.x = pack_bf(s0.x, s0.y);
        w.y = pack_bf(s0.z, s0.w);
        w.z = pack_bf(s1.x, s1.y);
        w.w = pack_bf(s1.z, s1.w);
        nt_store_u4(h_out + t, w);
    } else if (node < OUT_ROWS) {
        const float4* er = ego_row(user, item, brand, node);
        float4 e0 = er[2 * q];
        float4 e1 = er[2 * q + 1];
        uint4 w1 = nt_load_u4(h1 + t);
        uint4 w2 = nt_load_u4(h2 + t);
        float4 o0, o1;
        o0.x = (e0.x + bf_lo(w1.x) + bf_lo(w2.x) + s0.x) * 0.25f;
        o0.y = (e0.y + bf_hi(w1.x) + bf_hi(w2.x) + s0.y) * 0.25f;
        o0.z = (e0.z + bf_lo(w1.y) + bf_lo(w2.y) + s0.z) * 0.25f;
        o0.w = (e0.w + bf_hi(w1.y) + bf_hi(w2.y) + s0.w) * 0.25f;
        o1.x = (e1.x + bf_lo(w1.z) + bf_lo(w2.z) + s1.x) * 0.25f;
        o1.y = (e1.y + bf_hi(w1.z) + bf_hi(w2.z) + s1.y) * 0.25f;
        o1.z = (e1.z + bf_lo(w1.w) + bf_lo(w2.w) + s1.z) * 0.25f;
        o1.w = (e1.w + bf_hi(w1.w) + bf_hi(w2.w) + s1.w) * 0.25f;
        float4* o = reinterpret_cast<float4*>(out) + t * 2;
        nt_store_f4(o,     o0);
        nt_store_f4(o + 1, o1);
    }
}

extern "C" void kernel_launch(void* const* d_in, const int* in_sizes, int n_in,
                              void* d_out, int out_size, void* d_ws, size_t ws_size,
                              hipStream_t stream) {
    const float* user  = (const float*)d_in[0];
    const float* item  = (const float*)d_in[1];
    const float* brand = (const float*)d_in[2];
    const float* vals  = (const float*)d_in[3];
    const int*   src   = (const int*)d_in[4];
    const int*   dst   = (const int*)d_in[5];
    float* out = (float*)d_out;

    // workspace layout (32-bit words); 16B alignment for uint4 arrays
    size_t W = 0;
    uint4* h1  = (uint4*)d_ws;                 W += (size_t)N_NODES * 32;   // bf16 rows (128B)
    uint4* h2  = (uint4*)((int*)d_ws + W);     W += (size_t)N_NODES * 32;
    uint2* csr = (uint2*)((int*)d_ws + W);     W += (size_t)N_EDGES * 2;
    int* rank      = (int*)d_ws + W;           W += N_EDGES;
    int* rowptr    = (int*)d_ws + W;           W += N_NODES + 2;
    int* counts    = (int*)d_ws + W;           W += N_NODES;
    int* blockSums = (int*)d_ws + W;           W += 512;
    (void)ws_size; (void)n_in; (void)in_sizes; (void)out_size;

    const int edgeBlocks   = (N_EDGES + 255) / 256;     // 4688
    const int gatherBlocks = (N_NODES * 8) / 256;       // 9375 (8 thr/node)

    // zero degree counters (poisoned workspace, and hist accumulates)
    hipMemsetAsync(counts, 0, (size_t)N_NODES * sizeof(int), stream);

    // build dst-sorted CSR: hist+rank -> scan -> XCD-binned record scatter
    lgcn_hist   <<<edgeBlocks, 256, 0, stream>>>(dst, counts, rank);
    lgcn_scan_p1<<<NB, 256, 0, stream>>>(counts, rowptr, blockSums);
    lgcn_scan_p2<<<1, 512, 0, stream>>>(blockSums);
    lgcn_scan_p3<<<NB, 256, 0, stream>>>(rowptr, blockSums);
    lgcn_csr_bin<<<NBIN * edgeBlocks, 256, 0, stream>>>(src, dst, vals, rank,
                                                        rowptr, csr);

    // 3 atomic-free SpMM layers (bf16 intermediates); residual fused in L3
    lgcn_gather<1><<<gatherBlocks, 256, 0, stream>>>(rowptr, csr, user, item, brand,
                                                     h1, h2, h1, out);
    lgcn_gather<2><<<gatherBlocks, 256, 0, stream>>>(rowptr, csr, user, item, brand,
                                                     h1, h2, h2, out);
    lgcn_gather<3><<<gatherBlocks, 256, 0, stream>>>(rowptr, csr, user, item, brand,
                                                     h1, h2, nullptr, out);
}

// Round 9
// 278.029 us; speedup vs baseline: 1.1603x; 1.1603x over previous
//
#include <hip/hip_runtime.h>

#define NUM_USERS  150000
#define NUM_ITEMS  140000
#define NUM_BRANDS 10000
#define N_NODES    300000
#define DIM        64
#define N_EDGES    1200000
#define OUT_ROWS   290000          // users + items

#define CHUNK      1024            // elements per scan block
#define NB         ((N_NODES + CHUNK - 1) / CHUNK)   // 293 scan blocks

#define NBIN       8               // one bin per XCD
#define BINSZ      (N_EDGES / NBIN)                  // 150000 csr records/bin

// ---------------------------------------------------------------------------
// bf16 helpers (h1/h2 stored as packed bf16: 64 dims = 8 uint4 per row)
// ---------------------------------------------------------------------------
__device__ __forceinline__ float bf_lo(unsigned u) { return __uint_as_float(u << 16); }
__device__ __forceinline__ float bf_hi(unsigned u) { return __uint_as_float(u & 0xffff0000u); }
__device__ __forceinline__ unsigned pack_bf(float a, float b) {
    unsigned ua = __float_as_uint(a); ua += 0x7fffu + ((ua >> 16) & 1u);
    unsigned ub = __float_as_uint(b); ub += 0x7fffu + ((ub >> 16) & 1u);
    return (ua >> 16) | (ub & 0xffff0000u);
}

// ---------------------------------------------------------------------------
// histogram of destination degrees + per-edge rank within its row
// ---------------------------------------------------------------------------
__global__ void lgcn_hist(const int* __restrict__ dst,
                          int* __restrict__ counts,
                          int* __restrict__ rank) {
    int e = blockIdx.x * blockDim.x + threadIdx.x;
    if (e >= N_EDGES) return;
    rank[e] = atomicAdd(&counts[dst[e]], 1);
}

// ---------------------------------------------------------------------------
// scan phase 1: per-1024-chunk exclusive scan (256 thr x 4 elem), chunk sums
// ---------------------------------------------------------------------------
__global__ void lgcn_scan_p1(const int* __restrict__ counts,
                             int* __restrict__ rowptr,
                             int* __restrict__ blockSums) {
    __shared__ int ts[256];
    int b    = blockIdx.x;
    int base = b * CHUNK;
    int t    = threadIdx.x;
    int c[4];
    int s = 0;
#pragma unroll
    for (int i = 0; i < 4; ++i) {
        int g = base + t * 4 + i;
        c[i] = (g < N_NODES) ? counts[g] : 0;
        s += c[i];
    }
    ts[t] = s;
    __syncthreads();
    for (int off = 1; off < 256; off <<= 1) {
        int v = (t >= off) ? ts[t - off] : 0;
        __syncthreads();
        ts[t] += v;
        __syncthreads();
    }
    int run = ts[t] - s;     // exclusive prefix of this thread's 4-group
#pragma unroll
    for (int i = 0; i < 4; ++i) {
        int g = base + t * 4 + i;
        if (g < N_NODES) rowptr[g] = run;
        run += c[i];
    }
    if (t == 255) blockSums[b] = ts[255];
}

// ---------------------------------------------------------------------------
// scan phase 2: single block exclusive-scans the NB (=293) chunk sums
// ---------------------------------------------------------------------------
__global__ void lgcn_scan_p2(int* __restrict__ blockSums) {
    __shared__ int sh[512];
    int t = threadIdx.x;
    int v = (t < NB) ? blockSums[t] : 0;
    sh[t] = v;
    __syncthreads();
    for (int off = 1; off < 512; off <<= 1) {
        int u = (t >= off) ? sh[t - off] : 0;
        __syncthreads();
        sh[t] += u;
        __syncthreads();
    }
    if (t < NB) blockSums[t] = sh[t] - v;   // exclusive
}

// ---------------------------------------------------------------------------
// scan phase 3: add chunk offsets; rowptr[N_NODES] = N_EDGES
// ---------------------------------------------------------------------------
__global__ void lgcn_scan_p3(int* __restrict__ rowptr,
                             const int* __restrict__ blockSums) {
    int b    = blockIdx.x;
    int base = b * CHUNK;
    int t    = threadIdx.x;
    int off  = blockSums[b];
#pragma unroll
    for (int i = 0; i < 4; ++i) {
        int g = base + t * 4 + i;
        if (g < N_NODES) rowptr[g] += off;
    }
    if (b == 0 && t == 0) rowptr[N_NODES] = N_EDGES;
}

// ---------------------------------------------------------------------------
// part: ONE read-once pass. Each block bins its 256 edges by position-bin
// (pos/BINSZ) via LDS counters, reserves per-bin runs with 8 global cursors,
// appends (src,val,pos) records to per-bin staging -> chunked-sequential
// writes (full lines, no scatter amp).
// ---------------------------------------------------------------------------
__global__ void lgcn_part(const int*   __restrict__ src,
                          const int*   __restrict__ dst,
                          const float* __restrict__ vals,
                          const int*   __restrict__ rank,
                          const int*   __restrict__ rowptr,
                          int*         __restrict__ cursor8,
                          uint4*       __restrict__ binBuf) {
    __shared__ int cnt[NBIN];
    __shared__ int base[NBIN];
    int t = threadIdx.x;
    int e = blockIdx.x * blockDim.x + t;
    if (t < NBIN) cnt[t] = 0;
    __syncthreads();
    int bin = 0, lr = 0;
    uint4 rec;
    bool valid = (e < N_EDGES);
    if (valid) {
        int pos = rowptr[dst[e]] + rank[e];
        bin = pos / BINSZ;
        lr  = atomicAdd(&cnt[bin], 1);
        rec.x = (unsigned)src[e];
        rec.y = __float_as_uint(vals[e]);
        rec.z = (unsigned)pos;
        rec.w = 0;
    }
    __syncthreads();
    if (t < NBIN) base[t] = atomicAdd(&cursor8[t], cnt[t]);
    __syncthreads();
    if (valid) binBuf[(size_t)bin * BINSZ + base[bin] + lr] = rec;
}

// ---------------------------------------------------------------------------
// fill: bin = blockIdx&7 -> XCD-local (dispatch round-robins XCDs). Each
// bin's blocks sequentially read their 2.4MB staging slice and scatter 8B
// records into the bin's 1.2MB csr window: stream + dirty region both fit
// the XCD's 4MB L2 -> dirty lines survive until full -> no write amp.
// ---------------------------------------------------------------------------
__global__ void lgcn_fill(const uint4* __restrict__ binBuf,
                          uint2*       __restrict__ csr) {
    int b   = blockIdx.x;
    int bin = b & (NBIN - 1);
    int i   = (b >> 3) * blockDim.x + threadIdx.x;
    if (i >= BINSZ) return;
    uint4 rec = binBuf[(size_t)bin * BINSZ + i];
    csr[rec.z] = make_uint2(rec.x, rec.y);
}

// ---------------------------------------------------------------------------
// ego row lookup: concat(user,item,brand) without materializing the concat
// ---------------------------------------------------------------------------
__device__ __forceinline__ const float4* ego_row(const float* __restrict__ user,
                                                 const float* __restrict__ item,
                                                 const float* __restrict__ brand,
                                                 int r) {
    if (r < NUM_USERS)
        return reinterpret_cast<const float4*>(user) + (r << 4);
    else if (r < NUM_USERS + NUM_ITEMS)
        return reinterpret_cast<const float4*>(item) + ((r - NUM_USERS) << 4);
    else
        return reinterpret_cast<const float4*>(brand) + ((r - NUM_USERS - NUM_ITEMS) << 4);
}

// row load, 8 floats per lane (8 lanes per row).
// LAYER 1: fp32 ego row (2x float4). LAYER 2/3: bf16 h row (1x uint4).
template <int LAYER>
__device__ __forceinline__ void load8(const float* __restrict__ user,
                                      const float* __restrict__ item,
                                      const float* __restrict__ brand,
                                      const uint4* __restrict__ h_src,
                                      int r, int q, float4& a, float4& b) {
    if (LAYER == 1) {
        const float4* er = ego_row(user, item, brand, r);
        a = er[2 * q];
        b = er[2 * q + 1];
    } else {
        uint4 w = h_src[(r << 3) + q];
        a = make_float4(bf_lo(w.x), bf_hi(w.x), bf_lo(w.y), bf_hi(w.y));
        b = make_float4(bf_lo(w.z), bf_hi(w.z), bf_lo(w.w), bf_hi(w.w));
    }
}

// ---------------------------------------------------------------------------
// gather SpMM: 8 lanes per dst node (8 dims/lane), 8 nodes per wave.
// 2-deep software pipeline (R7 known-good). LAYER=1: ego(fp32)->h1(bf16).
// LAYER=2: h1->h2. LAYER=3: h2 -> fused out = (ego + h1 + h2 + sum) * 0.25.
// ---------------------------------------------------------------------------
template <int LAYER>
__global__ void lgcn_gather(const int*   __restrict__ rowptr,
                            const uint2* __restrict__ csr,
                            const float* __restrict__ user,
                            const float* __restrict__ item,
                            const float* __restrict__ brand,
                            const uint4* __restrict__ h1,
                            const uint4* __restrict__ h2,
                            uint4*       __restrict__ h_out,
                            float*       __restrict__ out) {
    int t    = blockIdx.x * blockDim.x + threadIdx.x;   // node*8 + q
    int node = t >> 3;
    int q    = t & 7;
    int beg = rowptr[node];
    int end = rowptr[node + 1];
    const uint4* h_src = (LAYER == 2) ? h1 : h2;        // LAYER 1 ignores this
    float4 s0 = make_float4(0.f, 0.f, 0.f, 0.f);
    float4 s1 = make_float4(0.f, 0.f, 0.f, 0.f);
    if (beg < end) {
        uint2 rec0 = csr[beg];
        uint2 rec1 = csr[(beg + 1 < end) ? beg + 1 : beg];
        float4 a0, b0;
        load8<LAYER>(user, item, brand, h_src, (int)rec0.x, q, a0, b0);
        for (int j = beg; j < end; ++j) {
            int jn = j + 2 < end ? j + 2 : end - 1;
            uint2 rec2 = csr[jn];                       // prefetch rec, 2 ahead
            float4 a1, b1;
            load8<LAYER>(user, item, brand, h_src, (int)rec1.x, q, a1, b1);
            float v = __uint_as_float(rec0.y);
            s0.x = fmaf(a0.x, v, s0.x);
            s0.y = fmaf(a0.y, v, s0.y);
            s0.z = fmaf(a0.z, v, s0.z);
            s0.w = fmaf(a0.w, v, s0.w);
            s1.x = fmaf(b0.x, v, s1.x);
            s1.y = fmaf(b0.y, v, s1.y);
            s1.z = fmaf(b0.z, v, s1.z);
            s1.w = fmaf(b0.w, v, s1.w);
            rec0 = rec1; rec1 = rec2; a0 = a1; b0 = b1;
        }
    }
    if (LAYER != 3) {
        uint4 w;
        w.x = pack_bf(s0.x, s0.y);
        w.y = pack_bf(s0.z, s0.w);
        w.z = pack_bf(s1.x, s1.y);
        w.w = pack_bf(s1.z, s1.w);
        h_out[t] = w;
    } else if (node < OUT_ROWS) {
        const float4* er = ego_row(user, item, brand, node);
        float4 e0 = er[2 * q];
        float4 e1 = er[2 * q + 1];
        uint4 w1 = h1[t];
        uint4 w2 = h2[t];
        float4 o0, o1;
        o0.x = (e0.x + bf_lo(w1.x) + bf_lo(w2.x) + s0.x) * 0.25f;
        o0.y = (e0.y + bf_hi(w1.x) + bf_hi(w2.x) + s0.y) * 0.25f;
        o0.z = (e0.z + bf_lo(w1.y) + bf_lo(w2.y) + s0.z) * 0.25f;
        o0.w = (e0.w + bf_hi(w1.y) + bf_hi(w2.y) + s0.w) * 0.25f;
        o1.x = (e1.x + bf_lo(w1.z) + bf_lo(w2.z) + s1.x) * 0.25f;
        o1.y = (e1.y + bf_hi(w1.z) + bf_hi(w2.z) + s1.y) * 0.25f;
        o1.z = (e1.z + bf_lo(w1.w) + bf_lo(w2.w) + s1.z) * 0.25f;
        o1.w = (e1.w + bf_hi(w1.w) + bf_hi(w2.w) + s1.w) * 0.25f;
        float4* o = reinterpret_cast<float4*>(out) + t * 2;
        o[0] = o0;
        o[1] = o1;
    }
}

extern "C" void kernel_launch(void* const* d_in, const int* in_sizes, int n_in,
                              void* d_out, int out_size, void* d_ws, size_t ws_size,
                              hipStream_t stream) {
    const float* user  = (const float*)d_in[0];
    const float* item  = (const float*)d_in[1];
    const float* brand = (const float*)d_in[2];
    const float* vals  = (const float*)d_in[3];
    const int*   src   = (const int*)d_in[4];
    const int*   dst   = (const int*)d_in[5];
    float* out = (float*)d_out;

    // workspace layout (32-bit words); 16B alignment holds for uint4 arrays
    size_t W = 0;
    uint4* h1  = (uint4*)d_ws;                 W += (size_t)N_NODES * 32;   // bf16 rows (128B)
    uint4* h2  = (uint4*)((int*)d_ws + W);     W += (size_t)N_NODES * 32;
    uint2* csr = (uint2*)((int*)d_ws + W);     W += (size_t)N_EDGES * 2;
    uint4* binBuf = (uint4*)((int*)d_ws + W);  W += (size_t)N_EDGES * 4;    // staging
    int* rank      = (int*)d_ws + W;           W += N_EDGES;
    int* rowptr    = (int*)d_ws + W;           W += N_NODES + 2;
    int* counts    = (int*)d_ws + W;           W += N_NODES;
    int* cursor8   = (int*)d_ws + W;           W += 16;
    int* blockSums = (int*)d_ws + W;           W += 512;
    (void)ws_size; (void)n_in; (void)in_sizes; (void)out_size;

    const int edgeBlocks   = (N_EDGES + 255) / 256;     // 4688
    const int fillBlocks   = NBIN * ((BINSZ + 255) / 256);  // 8*586
    const int gatherBlocks = (N_NODES * 8) / 256;       // 9375 (8 thr/node)

    // zero degree counters + bin cursors (workspace is poisoned)
    hipMemsetAsync(counts, 0, (size_t)(N_NODES + 16) * sizeof(int), stream);

    // build dst-sorted CSR: hist+rank -> scan -> part (read-once, seq write)
    //                       -> fill (XCD-local 1.2MB scatter, L2-contained)
    lgcn_hist   <<<edgeBlocks, 256, 0, stream>>>(dst, counts, rank);
    lgcn_scan_p1<<<NB, 256, 0, stream>>>(counts, rowptr, blockSums);
    lgcn_scan_p2<<<1, 512, 0, stream>>>(blockSums);
    lgcn_scan_p3<<<NB, 256, 0, stream>>>(rowptr, blockSums);
    lgcn_part   <<<edgeBlocks, 256, 0, stream>>>(src, dst, vals, rank, rowptr,
                                                 cursor8, binBuf);
    lgcn_fill   <<<fillBlocks, 256, 0, stream>>>(binBuf, csr);

    // 3 atomic-free SpMM layers (bf16 intermediates); residual fused in L3
    lgcn_gather<1><<<gatherBlocks, 256, 0, stream>>>(rowptr, csr, user, item, brand,
                                                     h1, h2, h1, out);
    lgcn_gather<2><<<gatherBlocks, 256, 0, stream>>>(rowptr, csr, user, item, brand,
                                                     h1, h2, h2, out);
    lgcn_gather<3><<<gatherBlocks, 256, 0, stream>>>(rowptr, csr, user, item, brand,
                                                     h1, h2, nullptr, out);
}